// Round 2
// 2270.687 us; speedup vs baseline: 2.6834x; 2.6834x over previous
//
#include <hip/hip_runtime.h>
#include <hip/hip_bf16.h>
#include <math.h>

// Problem dims (fixed by the reference)
#define RB 64
#define RS 512
#define RE 1024
#define RH 1024
#define BSH ((size_t)RB * RS * RH)

// scan decomposition: 256 blocks = 64 col-groups x 4 row-groups.
// The 4 row groups are INDEPENDENT scans (disjoint batch rows): each has its
// own flat 64-arrival barrier (round-0-proven structure), on its own lines.
#define NBLK 256

typedef __attribute__((ext_vector_type(8))) __bf16 bf16x8;
typedef __attribute__((ext_vector_type(4))) float  f32x4;

__device__ __forceinline__ bf16x8 cvt8(f32x4 a, f32x4 b) {
    bf16x8 r;
    r[0] = (__bf16)a[0]; r[1] = (__bf16)a[1];
    r[2] = (__bf16)a[2]; r[3] = (__bf16)a[3];
    r[4] = (__bf16)b[0]; r[5] = (__bf16)b[1];
    r[6] = (__bf16)b[2]; r[7] = (__bf16)b[3];
    return r;
}

// L2-bypassing (agent-scope => L3 coherent point) accessors for cross-XCD data.
__device__ __forceinline__ bf16x8 ld_frag_agent(const unsigned long long* p) {
    union { unsigned long long u[2]; bf16x8 v; } r;
    r.u[0] = __hip_atomic_load(p,     __ATOMIC_RELAXED, __HIP_MEMORY_SCOPE_AGENT);
    r.u[1] = __hip_atomic_load(p + 1, __ATOMIC_RELAXED, __HIP_MEMORY_SCOPE_AGENT);
    return r.v;
}
__device__ __forceinline__ void st_bf16_agent(__bf16* p, float v) {
    union { __bf16 b; unsigned short s; } u;
    u.b = (__bf16)v;
    __hip_atomic_store(reinterpret_cast<unsigned short*>(p), u.s,
                       __ATOMIC_RELAXED, __HIP_MEMORY_SCOPE_AGENT);
}

// ---------------------------------------------------------------------------
// Phase 0: zero barrier state (d_ws is re-poisoned each call).
// sync layout (u32): counter[rg] at rg*32 (rg<4), epoch[rg] at 128 + rg*32.
// ---------------------------------------------------------------------------
__global__ void init_flags_k(unsigned* sync) {
    if (threadIdx.x < 256) sync[threadIdx.x] = 0u;
}

// ---------------------------------------------------------------------------
// Phase 1: wx[m,h] = sum_e x[m,e]*W_w[h,e] + W_b[h]
// 128x128 tile, BK=64, reg-staged fp32->bf16 into padded LDS, 2x2 wave grid,
// 4x4 16x16x32 MFMA fragments per wave. Written into Out's result1 region.
// ---------------------------------------------------------------------------
#define WBK  64
#define LDST 72   // 64 + 8 pad bf16 elems; 144 B row stride (16B-aligned)

__global__ __launch_bounds__(256) void wx_gemm(
    const float* __restrict__ X,
    const float* __restrict__ Ww,
    const float* __restrict__ Wb,
    float* __restrict__ Out)
{
    __shared__ __align__(16) __bf16 As[128 * LDST];
    __shared__ __align__(16) __bf16 Bs[128 * LDST];

    const int tid  = threadIdx.x;
    const int lane = tid & 63;
    const int wave = tid >> 6;
    const int m0   = blockIdx.y * 128;
    const int n0   = blockIdx.x * 128;
    const int wm   = (wave >> 1) * 64;   // wave's m-offset within tile
    const int wn   = (wave & 1) * 64;    // wave's n-offset within tile

    // staging map: thread -> (row = tid>>3 in 0..31, 8-elem k-chunk = (tid&7)*8)
    const int sk   = (tid & 7) * 8;
    const int srow = tid >> 3;

    f32x4 acc[4][4];
#pragma unroll
    for (int i = 0; i < 4; ++i)
#pragma unroll
        for (int j = 0; j < 4; ++j) acc[i][j] = (f32x4){0.f, 0.f, 0.f, 0.f};

    for (int kc = 0; kc < RE; kc += WBK) {
#pragma unroll
        for (int rr = 0; rr < 128; rr += 32) {
            const float* xp = X + (size_t)(m0 + srow + rr) * RE + kc + sk;
            *reinterpret_cast<bf16x8*>(&As[(srow + rr) * LDST + sk]) =
                cvt8(*reinterpret_cast<const f32x4*>(xp),
                     *reinterpret_cast<const f32x4*>(xp + 4));
            const float* wp = Ww + (size_t)(n0 + srow + rr) * RE + kc + sk;
            *reinterpret_cast<bf16x8*>(&Bs[(srow + rr) * LDST + sk]) =
                cvt8(*reinterpret_cast<const f32x4*>(wp),
                     *reinterpret_cast<const f32x4*>(wp + 4));
        }
        __syncthreads();

#pragma unroll
        for (int ks = 0; ks < 2; ++ks) {
            bf16x8 af[4], bfr[4];
#pragma unroll
            for (int i = 0; i < 4; ++i) {
                af[i]  = *reinterpret_cast<const bf16x8*>(
                    &As[(wm + i * 16 + (lane & 15)) * LDST + ks * 32 + (lane >> 4) * 8]);
                bfr[i] = *reinterpret_cast<const bf16x8*>(
                    &Bs[(wn + i * 16 + (lane & 15)) * LDST + ks * 32 + (lane >> 4) * 8]);
            }
#pragma unroll
            for (int i = 0; i < 4; ++i)
#pragma unroll
                for (int j = 0; j < 4; ++j)
                    acc[i][j] = __builtin_amdgcn_mfma_f32_16x16x32_bf16(
                        af[i], bfr[j], acc[i][j], 0, 0, 0);
        }
        __syncthreads();
    }

    // C/D layout: col = lane&15, row = (lane>>4)*4 + r
    const int col = lane & 15, rbase = (lane >> 4) * 4;
#pragma unroll
    for (int j = 0; j < 4; ++j) {
        const int n = n0 + wn + j * 16 + col;
        const float bias = Wb[n];
#pragma unroll
        for (int i = 0; i < 4; ++i) {
#pragma unroll
            for (int r = 0; r < 4; ++r) {
                const int m = m0 + wm + i * 16 + rbase + r;
                Out[(size_t)m * RH + n] = acc[i][j][r] + bias;
            }
        }
    }
}

// ---------------------------------------------------------------------------
// Flat 64-arrival grid barrier, PER ROW GROUP (the 4 scans are independent).
//  * __syncthreads() drains each wave's vmcnt => this block's agent-scope
//    stores have completed at the L3 coherent point before we arrive.
//  * ONE atomicAdd per block on counter[rg]. Last arrival (old == 64g-1)
//    publishes epoch[rg] = g. Others poll epoch[rg] with a single lane,
//    paced by s_sleep (round-0-proven).
// ---------------------------------------------------------------------------
__device__ __forceinline__ void gbar_rg(unsigned* sync, unsigned g, int tid, int rg)
{
    __syncthreads();
    if (tid == 0) {
        unsigned old = __hip_atomic_fetch_add(&sync[rg * 32], 1u,
                                              __ATOMIC_RELAXED, __HIP_MEMORY_SCOPE_AGENT);
        if (old == 64u * g - 1u) {
            __hip_atomic_store(&sync[128 + rg * 32], g,
                               __ATOMIC_RELAXED, __HIP_MEMORY_SCOPE_AGENT);
        } else {
            while (__hip_atomic_load(&sync[128 + rg * 32],
                                     __ATOMIC_RELAXED, __HIP_MEMORY_SCOPE_AGENT) < g)
                __builtin_amdgcn_s_sleep(2);
        }
    }
    __syncthreads();
}

// ---------------------------------------------------------------------------
// Phase 2: persistent scan. 256 blocks x 256 thr. Block (cg,rg) owns the
// 16x16 output patch rows [16rg,16rg+16) x cols [16cg,16cg+16). The 4 waves
// split K=1024 into 256 each (8 U-frags = 32 VGPRs/lane), partials reduced
// through 4 KB LDS, epilogue distributed over all 256 threads. Row groups
// are independent scans with independent barriers.
// ---------------------------------------------------------------------------
__global__ __launch_bounds__(256) void rnn_scan(
    const float* __restrict__ Uw,
    const float* __restrict__ Ub,
    float* Out,               // [B*S*H] (wx -> result1) then [B*H] t_final
    __bf16* hbuf,             // 2 * B * H bf16, double-buffered h3
    unsigned* sync)           // barrier state
{
    __shared__ float red[4 * 256];
    __shared__ float ubs[16];

    const int tid  = threadIdx.x;
    const int lane = tid & 63;
    const int wave = tid >> 6;           // K-slice index 0..3
    const int bid  = blockIdx.x;
    const int cg   = bid >> 2;           // column group 0..63
    const int rg   = bid & 3;            // row group 0..3 (independent scan)
    const int col0 = cg * 16;
    const int row0 = rg * 16;

    // --- register-resident U^T slice for this wave's K range ---
    // B-frag layout: n = lane&15, k = 256*wave + 32*j + (lane>>4)*8
    bf16x8 ufr[8];
    {
        const float* up = Uw + (size_t)(col0 + (lane & 15)) * RH
                        + 256 * wave + ((lane >> 4) * 8);
#pragma unroll
        for (int j = 0; j < 8; ++j)
            ufr[j] = cvt8(*reinterpret_cast<const f32x4*>(up + j * 32),
                          *reinterpret_cast<const f32x4*>(up + j * 32 + 4));
    }
    if (tid < 16) ubs[tid] = Ub[col0 + tid];

    // epilogue mapping: thread -> one element of the 16x16 patch
    const int erow = row0 + (tid >> 4);
    const int ecol = col0 + (tid & 15);

    // --- h3_0 = tanh(wx[:, 0, patch])  (t0 carry is zero) ---
    st_bf16_agent(hbuf + erow * RH + ecol,
                  tanhf(Out[(size_t)erow * RS * RH + ecol]));
    gbar_rg(sync, 1u, tid, rg);

    const int arow  = row0 + (lane & 15);          // batch row for A-frags
    const int kbase = 256 * wave + (lane >> 4) * 8;

    for (int t = 0; t < RS; ++t) {
        const __bf16* cur = hbuf + (size_t)(t & 1) * (RB * RH);
        __bf16*       nxt = hbuf + (size_t)((t + 1) & 1) * (RB * RH);
        const unsigned long long* cp =
            reinterpret_cast<const unsigned long long*>(cur)
            + ((size_t)arow * RH + kbase) / 4;

        // 8 independent A-frag loads (L3, cross-XCD): one latency round.
        bf16x8 x0 = ld_frag_agent(cp + 0 * 8);
        bf16x8 x1 = ld_frag_agent(cp + 1 * 8);
        bf16x8 x2 = ld_frag_agent(cp + 2 * 8);
        bf16x8 x3 = ld_frag_agent(cp + 3 * 8);
        bf16x8 x4 = ld_frag_agent(cp + 4 * 8);
        bf16x8 x5 = ld_frag_agent(cp + 5 * 8);
        bf16x8 x6 = ld_frag_agent(cp + 6 * 8);
        bf16x8 x7 = ld_frag_agent(cp + 7 * 8);

        // wx prefetch for this thread's epilogue element. Issued AFTER the
        // frag loads so the MFMA-path vmcnt waits never include this cold
        // HBM read; it drains for free at the reduce-__syncthreads.
        float wn = 0.f;
        if (t < RS - 1)
            wn = Out[(size_t)erow * RS * RH + (size_t)(t + 1) * RH + ecol];

        f32x4 ac0 = (f32x4){0.f, 0.f, 0.f, 0.f};
        f32x4 ac1 = ac0, ac2 = ac0, ac3 = ac0;
        ac0 = __builtin_amdgcn_mfma_f32_16x16x32_bf16(x0, ufr[0], ac0, 0, 0, 0);
        ac1 = __builtin_amdgcn_mfma_f32_16x16x32_bf16(x1, ufr[1], ac1, 0, 0, 0);
        ac2 = __builtin_amdgcn_mfma_f32_16x16x32_bf16(x2, ufr[2], ac2, 0, 0, 0);
        ac3 = __builtin_amdgcn_mfma_f32_16x16x32_bf16(x3, ufr[3], ac3, 0, 0, 0);
        ac0 = __builtin_amdgcn_mfma_f32_16x16x32_bf16(x4, ufr[4], ac0, 0, 0, 0);
        ac1 = __builtin_amdgcn_mfma_f32_16x16x32_bf16(x5, ufr[5], ac1, 0, 0, 0);
        ac2 = __builtin_amdgcn_mfma_f32_16x16x32_bf16(x6, ufr[6], ac2, 0, 0, 0);
        ac3 = __builtin_amdgcn_mfma_f32_16x16x32_bf16(x7, ufr[7], ac3, 0, 0, 0);
        const f32x4 acc = (ac0 + ac1) + (ac2 + ac3);

        // cross-wave K reduction: [wave][row][col] fp32 partials
#pragma unroll
        for (int r = 0; r < 4; ++r)
            red[wave * 256 + ((lane >> 4) * 4 + r) * 16 + (lane & 15)] = acc[r];
        __syncthreads();

        const float v = red[tid] + red[256 + tid] + red[512 + tid] + red[768 + tid]
                      + ubs[tid & 15];
        const size_t oidx = (size_t)erow * RS * RH + (size_t)t * RH + ecol;
        Out[oidx] = v;
        if (t == RS - 1) {
            Out[BSH + (size_t)erow * RH + ecol] = v;    // t_final
        } else {
            st_bf16_agent(nxt + erow * RH + ecol, tanhf(wn + v));
            gbar_rg(sync, (unsigned)(t + 2), tid, rg);
        }
    }
}

// ---------------------------------------------------------------------------
extern "C" void kernel_launch(void* const* d_in, const int* in_sizes, int n_in,
                              void* d_out, int out_size, void* d_ws, size_t ws_size,
                              hipStream_t stream)
{
    const float* X  = (const float*)d_in[0];   // [B,S,E] fp32
    const float* Ww = (const float*)d_in[1];   // [H,E]   fp32
    const float* Wb = (const float*)d_in[2];   // [H]     fp32
    const float* Uw = (const float*)d_in[3];   // [H,H]   fp32
    const float* Ub = (const float*)d_in[4];   // [H]     fp32
    float* Out = (float*)d_out;                // [B*S*H] result1 + [B*H] t_final

    __bf16* hbuf = (__bf16*)d_ws;              // 2*B*H bf16 = 256 KB
    unsigned* sync = (unsigned*)((char*)d_ws + (size_t)2 * RB * RH * sizeof(__bf16));

    hipLaunchKernelGGL(init_flags_k, dim3(1), dim3(256), 0, stream, sync);
    hipLaunchKernelGGL(wx_gemm, dim3(RH / 128, (RB * RS) / 128), dim3(256), 0, stream,
                       X, Ww, Wb, Out);
    hipLaunchKernelGGL(rnn_scan, dim3(NBLK), dim3(256), 0, stream,
                       Uw, Ub, Out, hbuf, sync);
}

// Round 5
// 2242.274 us; speedup vs baseline: 2.7174x; 1.0127x over previous
//
#include <hip/hip_runtime.h>
#include <hip/hip_bf16.h>
#include <math.h>

// Problem dims (fixed by the reference)
#define RB 64
#define RS 512
#define RE 1024
#define RH 1024
#define BSH ((size_t)RB * RS * RH)

// scan decomposition: 256 blocks = 64 col-groups x 4 row-groups.
// The 4 row groups are INDEPENDENT scans (disjoint batch rows).
// Sync: each block owns flag SLOT rg*64+cg (NOT bid! bid = cg*4+rg — round-4's
// bug was polling a contiguous flags[rg*64..] range while storing at bid).
// flag[slot] = g means that block finished step g-2 and its h3_{g-1} agent-
// scope publishes are visible at L3 (flag stored after a __syncthreads that
// drains vmcnt). Consumer at step t polls its row group's 64 contiguous slots
// with ONE coalesced wave load (lane l = cg l) and __all(f >= t+1).
// Flag t+1 from a block also proves it finished its step t-1 READS of buffer
// (t-1)&1, so writing h3_{t+1} into buffer (t+1)&1 during step t can never
// overwrite unread data (ping-pong induction, as in rounds 0-2).
// Workspace: hbuf 256 KB + flags 1 KB == footprint proven in rounds 0-2.
#define NBLK 256

typedef __attribute__((ext_vector_type(8))) __bf16 bf16x8;
typedef __attribute__((ext_vector_type(4))) float  f32x4;

__device__ __forceinline__ bf16x8 cvt8(f32x4 a, f32x4 b) {
    bf16x8 r;
    r[0] = (__bf16)a[0]; r[1] = (__bf16)a[1];
    r[2] = (__bf16)a[2]; r[3] = (__bf16)a[3];
    r[4] = (__bf16)b[0]; r[5] = (__bf16)b[1];
    r[6] = (__bf16)b[2]; r[7] = (__bf16)b[3];
    return r;
}

// L2-bypassing (agent-scope => L3 coherent point) accessors for cross-XCD data.
__device__ __forceinline__ bf16x8 ld_frag_agent(const unsigned long long* p) {
    union { unsigned long long u[2]; bf16x8 v; } r;
    r.u[0] = __hip_atomic_load(p,     __ATOMIC_RELAXED, __HIP_MEMORY_SCOPE_AGENT);
    r.u[1] = __hip_atomic_load(p + 1, __ATOMIC_RELAXED, __HIP_MEMORY_SCOPE_AGENT);
    return r.v;
}
__device__ __forceinline__ void st_bf16_agent(__bf16* p, float v) {
    union { __bf16 b; unsigned short s; } u;
    u.b = (__bf16)v;
    __hip_atomic_store(reinterpret_cast<unsigned short*>(p), u.s,
                       __ATOMIC_RELAXED, __HIP_MEMORY_SCOPE_AGENT);
}

// ---------------------------------------------------------------------------
// Phase 0: zero the 256 progress flags (d_ws is re-poisoned each call).
// ---------------------------------------------------------------------------
__global__ void init_flags_k(unsigned* flags) {
    if (threadIdx.x < NBLK) flags[threadIdx.x] = 0u;
}

// ---------------------------------------------------------------------------
// Phase 1: wx[m,h] = sum_e x[m,e]*W_w[h,e] + W_b[h]
// 128x128 tile, BK=64, reg-staged fp32->bf16 into padded LDS, 2x2 wave grid,
// 4x4 16x16x32 MFMA fragments per wave. (unchanged from round 2 — known good)
// ---------------------------------------------------------------------------
#define WBK  64
#define LDST 72   // 64 + 8 pad bf16 elems; 144 B row stride (16B-aligned)

__global__ __launch_bounds__(256) void wx_gemm(
    const float* __restrict__ X,
    const float* __restrict__ Ww,
    const float* __restrict__ Wb,
    float* __restrict__ Out)
{
    __shared__ __align__(16) __bf16 As[128 * LDST];
    __shared__ __align__(16) __bf16 Bs[128 * LDST];

    const int tid  = threadIdx.x;
    const int lane = tid & 63;
    const int wave = tid >> 6;
    const int m0   = blockIdx.y * 128;
    const int n0   = blockIdx.x * 128;
    const int wm   = (wave >> 1) * 64;
    const int wn   = (wave & 1) * 64;

    const int sk   = (tid & 7) * 8;
    const int srow = tid >> 3;

    f32x4 acc[4][4];
#pragma unroll
    for (int i = 0; i < 4; ++i)
#pragma unroll
        for (int j = 0; j < 4; ++j) acc[i][j] = (f32x4){0.f, 0.f, 0.f, 0.f};

    for (int kc = 0; kc < RE; kc += WBK) {
#pragma unroll
        for (int rr = 0; rr < 128; rr += 32) {
            const float* xp = X + (size_t)(m0 + srow + rr) * RE + kc + sk;
            *reinterpret_cast<bf16x8*>(&As[(srow + rr) * LDST + sk]) =
                cvt8(*reinterpret_cast<const f32x4*>(xp),
                     *reinterpret_cast<const f32x4*>(xp + 4));
            const float* wp = Ww + (size_t)(n0 + srow + rr) * RE + kc + sk;
            *reinterpret_cast<bf16x8*>(&Bs[(srow + rr) * LDST + sk]) =
                cvt8(*reinterpret_cast<const f32x4*>(wp),
                     *reinterpret_cast<const f32x4*>(wp + 4));
        }
        __syncthreads();

#pragma unroll
        for (int ks = 0; ks < 2; ++ks) {
            bf16x8 af[4], bfr[4];
#pragma unroll
            for (int i = 0; i < 4; ++i) {
                af[i]  = *reinterpret_cast<const bf16x8*>(
                    &As[(wm + i * 16 + (lane & 15)) * LDST + ks * 32 + (lane >> 4) * 8]);
                bfr[i] = *reinterpret_cast<const bf16x8*>(
                    &Bs[(wn + i * 16 + (lane & 15)) * LDST + ks * 32 + (lane >> 4) * 8]);
            }
#pragma unroll
            for (int i = 0; i < 4; ++i)
#pragma unroll
                for (int j = 0; j < 4; ++j)
                    acc[i][j] = __builtin_amdgcn_mfma_f32_16x16x32_bf16(
                        af[i], bfr[j], acc[i][j], 0, 0, 0);
        }
        __syncthreads();
    }

    const int col = lane & 15, rbase = (lane >> 4) * 4;
#pragma unroll
    for (int j = 0; j < 4; ++j) {
        const int n = n0 + wn + j * 16 + col;
        const float bias = Wb[n];
#pragma unroll
        for (int i = 0; i < 4; ++i) {
#pragma unroll
            for (int r = 0; r < 4; ++r) {
                const int m = m0 + wm + i * 16 + rbase + r;
                Out[(size_t)m * RH + n] = acc[i][j][r] + bias;
            }
        }
    }
}

// ---------------------------------------------------------------------------
// Phase 2: persistent scan with flag-vector sync (slot = rg*64 + cg).
// 256 blocks x 256 thr. Block (cg,rg) owns the 16x16 output patch
// rows [16rg,16rg+16) x cols [16cg,16cg+16). 4 waves split K=1024 into 256
// each (8 U-frags = 32 VGPRs/lane); partials reduced through 4 KB LDS.
// ---------------------------------------------------------------------------
__global__ __launch_bounds__(256) void rnn_scan(
    const float* __restrict__ Uw,
    const float* __restrict__ Ub,
    float* Out,               // [B*S*H] (wx -> result1) then [B*H] t_final
    __bf16* hbuf,             // 2 * B * H bf16, double-buffered h3 (256 KB)
    unsigned* flags)          // 256 progress flags (1 KB), slot = rg*64+cg
{
    __shared__ float red[4 * 256];
    __shared__ float ubs[16];

    const int tid  = threadIdx.x;
    const int lane = tid & 63;
    const int wave = tid >> 6;           // K-slice index 0..3
    const int bid  = blockIdx.x;
    const int cg   = bid >> 2;           // column group 0..63
    const int rg   = bid & 3;            // row group 0..3 (independent scan)
    const int col0 = cg * 16;
    const int row0 = rg * 16;
    const int slot = rg * 64 + cg;       // THIS block's flag slot (round-4 fix)

    // --- register-resident U^T slice for this wave's K range ---
    // B-frag layout: n = lane&15, k = 256*wave + 32*j + (lane>>4)*8
    bf16x8 ufr[8];
    {
        const float* up = Uw + (size_t)(col0 + (lane & 15)) * RH
                        + 256 * wave + ((lane >> 4) * 8);
#pragma unroll
        for (int j = 0; j < 8; ++j)
            ufr[j] = cvt8(*reinterpret_cast<const f32x4*>(up + j * 32),
                          *reinterpret_cast<const f32x4*>(up + j * 32 + 4));
    }
    if (tid < 16) ubs[tid] = Ub[col0 + tid];

    // epilogue mapping: thread -> one element of the 16x16 patch
    const int erow = row0 + (tid >> 4);
    const int ecol = col0 + (tid & 15);

    // --- h3_0 = tanh(wx[:, 0, patch]) into buffer 0, then flag = 1 ---
    st_bf16_agent(hbuf + erow * RH + ecol,
                  tanhf(Out[(size_t)erow * RS * RH + ecol]));
    // 2-deep wx prefetch: wn_cur = wx(t+1) for the tanh at step t
    float wn_cur = Out[(size_t)erow * RS * RH + (size_t)1 * RH + ecol];
    __syncthreads();                         // drains the h3_0 stores (vmcnt)
    if (tid == 0)
        __hip_atomic_store(&flags[slot], 1u,
                           __ATOMIC_RELAXED, __HIP_MEMORY_SCOPE_AGENT);

    const int arow  = row0 + (lane & 15);          // batch row for A-frags
    const int kbase = 256 * wave + (lane >> 4) * 8;
    const unsigned* myflags = flags + rg * 64;     // this row group's 64 slots

    for (int t = 0; t < RS; ++t) {
        const __bf16* cur = hbuf + (size_t)(t & 1) * (RB * RH);
        __bf16*       nxt = hbuf + (size_t)((t + 1) & 1) * (RB * RH);
        const unsigned long long* cp =
            reinterpret_cast<const unsigned long long*>(cur)
            + ((size_t)arow * RH + kbase) / 4;

        // --- poll: one coalesced wave load of the 64 slots, all >= t+1 ---
        const unsigned tgt = (unsigned)(t + 1);
        while (true) {
            const unsigned f = __hip_atomic_load(&myflags[lane],
                                                 __ATOMIC_RELAXED,
                                                 __HIP_MEMORY_SCOPE_AGENT);
            if (__all(f >= tgt)) break;
            __builtin_amdgcn_s_sleep(1);
        }
        // acquire-substitute: forbid the compiler from hoisting the frag
        // loads above the relaxed spin (HW issue is in-order; rounds 0/2
        // were protected by the __syncthreads inside gbar).
        __builtin_amdgcn_sched_barrier(0);
        asm volatile("" ::: "memory");

        // 8 independent A-frag loads (L3, cross-XCD): one latency round.
        bf16x8 x0 = ld_frag_agent(cp + 0 * 8);
        bf16x8 x1 = ld_frag_agent(cp + 1 * 8);
        bf16x8 x2 = ld_frag_agent(cp + 2 * 8);
        bf16x8 x3 = ld_frag_agent(cp + 3 * 8);
        bf16x8 x4 = ld_frag_agent(cp + 4 * 8);
        bf16x8 x5 = ld_frag_agent(cp + 5 * 8);
        bf16x8 x6 = ld_frag_agent(cp + 6 * 8);
        bf16x8 x7 = ld_frag_agent(cp + 7 * 8);

        f32x4 ac0 = (f32x4){0.f, 0.f, 0.f, 0.f};
        f32x4 ac1 = ac0, ac2 = ac0, ac3 = ac0;
        ac0 = __builtin_amdgcn_mfma_f32_16x16x32_bf16(x0, ufr[0], ac0, 0, 0, 0);
        ac1 = __builtin_amdgcn_mfma_f32_16x16x32_bf16(x1, ufr[1], ac1, 0, 0, 0);
        ac2 = __builtin_amdgcn_mfma_f32_16x16x32_bf16(x2, ufr[2], ac2, 0, 0, 0);
        ac3 = __builtin_amdgcn_mfma_f32_16x16x32_bf16(x3, ufr[3], ac3, 0, 0, 0);
        ac0 = __builtin_amdgcn_mfma_f32_16x16x32_bf16(x4, ufr[4], ac0, 0, 0, 0);
        ac1 = __builtin_amdgcn_mfma_f32_16x16x32_bf16(x5, ufr[5], ac1, 0, 0, 0);
        ac2 = __builtin_amdgcn_mfma_f32_16x16x32_bf16(x6, ufr[6], ac2, 0, 0, 0);
        ac3 = __builtin_amdgcn_mfma_f32_16x16x32_bf16(x7, ufr[7], ac3, 0, 0, 0);
        const f32x4 acc = (ac0 + ac1) + (ac2 + ac3);

        // --- cross-wave K reduction ---
#pragma unroll
        for (int r = 0; r < 4; ++r)
            red[wave * 256 + ((lane >> 4) * 4 + r) * 16 + (lane & 15)] = acc[r];
        __syncthreads();

        const float v = red[tid] + red[256 + tid] + red[512 + tid] + red[768 + tid]
                      + ubs[tid & 15];
        const size_t oidx = (size_t)erow * RS * RH + (size_t)t * RH + ecol;
        if (t == RS - 1) {
            Out[oidx] = v;
            Out[BSH + (size_t)erow * RH + ecol] = v;    // t_final
        } else {
            // publish h3 FIRST (other blocks' critical path), then local work
            st_bf16_agent(nxt + erow * RH + ecol, tanhf(wn_cur + v));
            Out[oidx] = v;
            if (t < RS - 2)
                wn_cur = Out[(size_t)erow * RS * RH + (size_t)(t + 2) * RH + ecol];
            __syncthreads();                 // drains h3 publishes (vmcnt)
            if (tid == 0)
                __hip_atomic_store(&flags[slot], (unsigned)(t + 2),
                                   __ATOMIC_RELAXED, __HIP_MEMORY_SCOPE_AGENT);
        }
    }
}

// ---------------------------------------------------------------------------
extern "C" void kernel_launch(void* const* d_in, const int* in_sizes, int n_in,
                              void* d_out, int out_size, void* d_ws, size_t ws_size,
                              hipStream_t stream)
{
    const float* X  = (const float*)d_in[0];   // [B,S,E] fp32
    const float* Ww = (const float*)d_in[1];   // [H,E]   fp32
    const float* Wb = (const float*)d_in[2];   // [H]     fp32
    const float* Uw = (const float*)d_in[3];   // [H,H]   fp32
    const float* Ub = (const float*)d_in[4];   // [H]     fp32
    float* Out = (float*)d_out;                // [B*S*H] result1 + [B*H] t_final

    __bf16* hbuf = (__bf16*)d_ws;              // 2*B*H bf16 = 256 KB
    unsigned* flags = (unsigned*)((char*)d_ws + (size_t)2 * RB * RH * sizeof(__bf16));

    hipLaunchKernelGGL(init_flags_k, dim3(1), dim3(256), 0, stream, flags);
    hipLaunchKernelGGL(wx_gemm, dim3(RH / 128, (RB * RS) / 128), dim3(256), 0, stream,
                       X, Ww, Wb, Out);
    hipLaunchKernelGGL(rnn_scan, dim3(NBLK), dim3(256), 0, stream,
                       Uw, Ub, Out, hbuf, flags);
}